// Round 7
// baseline (918.008 us; speedup 1.0000x reference)
//
#include <hip/hip_runtime.h>

#define NU 100000
#define NI 50000
#define NE 1000000
#define NB 16384

#define UB ((NU + 1023) / 1024)   // 98 user scan blocks
#define IB ((NI + 1023) / 1024)   // 49 item scan blocks

// ---- degree count (int atomics) ----
__global__ void deg_kernel(const int* __restrict__ ei, int* du, int* di) {
    int e = blockIdx.x * blockDim.x + threadIdx.x;
    if (e >= NE) return;
    atomicAdd(&du[ei[e]], 1);
    atomicAdd(&di[ei[NE + e]], 1);
}

// ---- scan pass 1: per-block partial sums (+ fused rsd computation) ----
__global__ __launch_bounds__(1024) void scan1_kernel(
        const int* __restrict__ du, const int* __restrict__ di,
        int* __restrict__ psum, float* __restrict__ rsd_u, float* __restrict__ rsd_i) {
    int b = blockIdx.x, tid = threadIdx.x;
    int v = 0;
    if (b < UB) {
        int i = b * 1024 + tid;
        if (i < NU) {
            int d = du[i]; v = d;
            rsd_u[i] = d > 0 ? 1.0f / sqrtf((float)d) : 0.f;
        }
    } else {
        int i = (b - UB) * 1024 + tid;
        if (i < NI) {
            int d = di[i]; v = d;
            rsd_i[i] = d > 0 ? 1.0f / sqrtf((float)d) : 0.f;
        }
    }
    int s = v;
    #pragma unroll
    for (int off = 32; off > 0; off >>= 1) s += __shfl_xor(s, off);
    __shared__ int ws[16];
    if ((tid & 63) == 0) ws[tid >> 6] = s;
    __syncthreads();
    if (tid == 0) {
        int t = 0;
        #pragma unroll
        for (int w = 0; w < 16; ++w) t += ws[w];
        psum[b] = t;
    }
}

// ---- scan pass 2: exclusive scan of block partials (per segment) ----
__global__ __launch_bounds__(128) void scan2_kernel(int* __restrict__ psum) {
    int base = (blockIdx.x == 0) ? 0 : UB;
    int n = (blockIdx.x == 0) ? UB : IB;
    int tid = threadIdx.x;
    __shared__ int sh[128];
    int v = (tid < n) ? psum[base + tid] : 0;
    sh[tid] = v;
    __syncthreads();
    for (int off = 1; off < 128; off <<= 1) {
        int t = (tid >= off) ? sh[tid - off] : 0;
        __syncthreads();
        sh[tid] += t;
        __syncthreads();
    }
    if (tid < n) psum[base + tid] = sh[tid] - v;  // exclusive
}

// ---- scan pass 3: block-local exclusive scan + offset -> rowptr, cursor ----
__global__ __launch_bounds__(1024) void scan3_kernel(
        const int* __restrict__ du, const int* __restrict__ di,
        const int* __restrict__ psum,
        int* __restrict__ rp_u, int* __restrict__ rp_i,
        int* __restrict__ cur_u, int* __restrict__ cur_i) {
    int b = blockIdx.x, tid = threadIdx.x;
    const int* deg; int* rp; int* cur; int N; int i0;
    if (b < UB) { deg = du; rp = rp_u; cur = cur_u; N = NU; i0 = b * 1024; }
    else        { deg = di; rp = rp_i; cur = cur_i; N = NI; i0 = (b - UB) * 1024; }
    int i = i0 + tid;
    int v = (i < N) ? deg[i] : 0;
    __shared__ int sh[1024];
    sh[tid] = v;
    __syncthreads();
    for (int off = 1; off < 1024; off <<= 1) {
        int t = (tid >= off) ? sh[tid - off] : 0;
        __syncthreads();
        sh[tid] += t;
        __syncthreads();
    }
    int excl = sh[tid] - v + psum[b];
    if (i < N) { rp[i] = excl; cur[i] = excl; }
    if (b == 0 && tid == 0) { rp_u[NU] = NE; rp_i[NI] = NE; }
}

// ---- CSR fill: 2M int atomics ----
__global__ void fill_csr_kernel(const int* __restrict__ ei,
                                int* __restrict__ curu, int* __restrict__ curi,
                                int* __restrict__ csr_u, int* __restrict__ csr_i) {
    int e = blockIdx.x * blockDim.x + threadIdx.x;
    if (e >= NE) return;
    int s = ei[e], d = ei[NE + e];
    int si = atomicAdd(&curi[d], 1);
    csr_i[si] = s;
    int su = atomicAdd(&curu[s], 1);
    csr_u[su] = d;
}

// ---- Kernel A: gather phase, one wave per node, NO LDS (max occupancy) ----
// Batched neighbor meta: 1 coalesced load = 64 neighbor ids, 1 gather = their
// rsd; per neighbor then just 2 shfl + 1 row load + 2 fma.
// Writes acbuf[n][0:64]=rs*ss, acbuf[n][64:128]=x_own*sp; swbuf[n]=rs*sw.
__global__ __launch_bounds__(256) void gatherA_kernel(
        int N, const float* __restrict__ x_own, const float* __restrict__ emb_o,
        const int* __restrict__ rp, const int* __restrict__ cs,
        const float* __restrict__ rsd_own, const float* __restrict__ rsd_o,
        float* __restrict__ acbuf, float* __restrict__ swbuf) {
    int wv = (blockIdx.x * blockDim.x + threadIdx.x) >> 6;
    int lane = threadIdx.x & 63;
    if (wv >= N) return;
    int beg = rp[wv], end = rp[wv + 1];
    float sp = 0.f, ss = 0.f, swp = 0.f;
    for (int jj = beg; jj < end; jj += 64) {
        int m = min(64, end - jj);
        int idx = (lane < m) ? cs[jj + lane] : 0;
        float w = (lane < m) ? rsd_o[idx] : 0.f;
        swp += w;
        int t = 0;
        for (; t + 3 < m; t += 4) {
            int s0 = __shfl(idx, t),     s1 = __shfl(idx, t + 1);
            int s2 = __shfl(idx, t + 2), s3 = __shfl(idx, t + 3);
            float w0 = __shfl(w, t),     w1 = __shfl(w, t + 1);
            float w2 = __shfl(w, t + 2), w3 = __shfl(w, t + 3);
            float v0 = emb_o[(size_t)s0 * 64 + lane];
            float v1 = emb_o[(size_t)s1 * 64 + lane];
            float v2 = emb_o[(size_t)s2 * 64 + lane];
            float v3 = emb_o[(size_t)s3 * 64 + lane];
            sp += (v0 + v1) + (v2 + v3);
            ss += w0 * v0 + w1 * v1 + w2 * v2 + w3 * v3;
        }
        for (; t < m; ++t) {
            int s0 = __shfl(idx, t);
            float w0 = __shfl(w, t);
            float v0 = emb_o[(size_t)s0 * 64 + lane];
            sp += v0; ss += w0 * v0;
        }
    }
    #pragma unroll
    for (int off = 32; off > 0; off >>= 1) swp += __shfl_xor(swp, off);
    float rs = rsd_own[wv];
    acbuf[(size_t)wv * 128 + lane] = rs * ss;
    acbuf[(size_t)wv * 128 + 64 + lane] = x_own[(size_t)wv * 64 + lane] * sp;
    if (lane == 0) swbuf[wv] = rs * swp;
}

// ---- Kernel B: transform phase, 8 nodes per wave, W in 32KB LDS ----
// a/c quads read as broadcast global loads (L2/L3-hot acbuf); W reads are
// lane-stride-1 (conflict-free). out = leakyL2( a@W1 + c@W2 + sw*b1 + dg*b2 ).
#define TB 8
__global__ __launch_bounds__(256) void transformB_kernel(
        int N, const float* __restrict__ acbuf, const float* __restrict__ swbuf,
        const int* __restrict__ rp,
        const float* __restrict__ W1, const float* __restrict__ b1,
        const float* __restrict__ W2, const float* __restrict__ b2,
        float* __restrict__ out) {
    __shared__ float w1s[4096];
    __shared__ float w2s[4096];
    int tid = threadIdx.x;
    #pragma unroll
    for (int r = 0; r < 4; ++r) {
        *(float4*)&w1s[(r * 256 + tid) * 4] = *(const float4*)&W1[(r * 256 + tid) * 4];
        *(float4*)&w2s[(r * 256 + tid) * 4] = *(const float4*)&W2[(r * 256 + tid) * 4];
    }
    __syncthreads();
    int wv = tid >> 6, lane = tid & 63;
    int n0 = (blockIdx.x * 4 + wv) * TB;
    if (n0 >= N) return;
    float b1v = b1[lane], b2v = b2[lane];
    float acc[TB] = {0.f, 0.f, 0.f, 0.f, 0.f, 0.f, 0.f, 0.f};
    for (int kq = 0; kq < 16; ++kq) {
        float4 aq[TB], cq[TB];
        #pragma unroll
        for (int j = 0; j < TB; ++j) {
            int n = n0 + j; if (n >= N) n = N - 1;
            aq[j] = *(const float4*)&acbuf[(size_t)n * 128 + kq * 4];        // broadcast
            cq[j] = *(const float4*)&acbuf[(size_t)n * 128 + 64 + kq * 4];   // broadcast
        }
        #pragma unroll
        for (int kk = 0; kk < 4; ++kk) {
            int k = kq * 4 + kk;
            float w1v = w1s[k * 64 + lane];
            float w2v = w2s[k * 64 + lane];
            #pragma unroll
            for (int j = 0; j < TB; ++j)
                acc[j] += (&aq[j].x)[kk] * w1v + (&cq[j].x)[kk] * w2v;
        }
    }
    #pragma unroll
    for (int j = 0; j < TB; ++j) {
        int n = n0 + j;
        if (n >= N) break;
        float dgf = (float)(rp[n + 1] - rp[n]);
        float h = acc[j] + swbuf[n] * b1v + dgf * b2v;
        h = h >= 0.f ? h : 0.2f * h;
        float nsq = h * h;
        #pragma unroll
        for (int off = 32; off > 0; off >>= 1) nsq += __shfl_xor(nsq, off);
        float nrm = sqrtf(nsq);
        out[(size_t)n * 64 + lane] = h / fmaxf(nrm, 1e-12f);
    }
}

// ---- final gather of concatenated embeddings (float4) ----
__global__ void gather_kernel(const float* __restrict__ ue, const float* __restrict__ u1,
                              const float* __restrict__ u2, const float* __restrict__ ie,
                              const float* __restrict__ i1, const float* __restrict__ i2,
                              const int* __restrict__ users, const int* __restrict__ pos,
                              const int* __restrict__ neg, float4* __restrict__ out) {
    int idx = blockIdx.x * blockDim.x + threadIdx.x;     // float4 index
    if (idx >= 3 * NB * 48) return;
    int which = idx / (NB * 48);
    int rem = idx - which * (NB * 48);
    int b = rem / 48, c4 = rem - b * 48;                 // c4 in [0,48)
    int seg = c4 >> 4, cc = (c4 & 15) << 2;
    int row;
    const float* srcarr;
    if (which == 0) {
        row = users[b];
        srcarr = (seg == 0) ? ue : (seg == 1 ? u1 : u2);
    } else {
        row = (which == 1) ? pos[b] : neg[b];
        srcarr = (seg == 0) ? ie : (seg == 1 ? i1 : i2);
    }
    out[idx] = *(const float4*)&srcarr[(size_t)row * 64 + cc];
}

extern "C" void kernel_launch(void* const* d_in, const int* in_sizes, int n_in,
                              void* d_out, int out_size, void* d_ws, size_t ws_size,
                              hipStream_t stream) {
    const float* user_emb = (const float*)d_in[0];
    const float* item_emb = (const float*)d_in[1];
    const float* W1_0 = (const float*)d_in[2];
    const float* b1_0 = (const float*)d_in[3];
    const float* W2_0 = (const float*)d_in[4];
    const float* b2_0 = (const float*)d_in[5];
    const float* W1_1 = (const float*)d_in[6];
    const float* b1_1 = (const float*)d_in[7];
    const float* W2_1 = (const float*)d_in[8];
    const float* b2_1 = (const float*)d_in[9];
    const int* ei = (const int*)d_in[10];
    const int* users = (const int*)d_in[11];
    const int* pos = (const int*)d_in[12];
    const int* neg = (const int*)d_in[13];

    char* p = (char*)d_ws;
    int* du = (int*)p;        p += NU * 4;
    int* di = (int*)p;        p += NI * 4;
    float* rsd_u = (float*)p; p += NU * 4;
    float* rsd_i = (float*)p; p += NI * 4;
    int* psum = (int*)p;      p += (UB + IB) * 4;
    int* rp_u = (int*)p;      p += (NU + 1) * 4;
    int* rp_i = (int*)p;      p += (NI + 1) * 4;
    int* cur_u = (int*)p;     p += NU * 4;
    int* cur_i = (int*)p;     p += NI * 4;
    int* csr_u = (int*)p;     p += (size_t)NE * 4;
    int* csr_i = (int*)p;     p += (size_t)NE * 4;
    float* u1 = (float*)p;    p += (size_t)NU * 64 * 4;
    float* u2 = (float*)p;    p += (size_t)NU * 64 * 4;
    float* i1 = (float*)p;    p += (size_t)NI * 64 * 4;
    float* i2 = (float*)p;    p += (size_t)NI * 64 * 4;
    float* acbuf = (float*)p; p += (size_t)NU * 128 * 4;  // reused per direction
    float* swbuf = (float*)p; p += NU * 4;

    // zero the degree counters (ws is re-poisoned before every call)
    hipMemsetAsync(du, 0, (size_t)(NU + NI) * sizeof(int), stream);

    deg_kernel<<<(NE + 255) / 256, 256, 0, stream>>>(ei, du, di);
    scan1_kernel<<<UB + IB, 1024, 0, stream>>>(du, di, psum, rsd_u, rsd_i);
    scan2_kernel<<<2, 128, 0, stream>>>(psum);
    scan3_kernel<<<UB + IB, 1024, 0, stream>>>(du, di, psum, rp_u, rp_i, cur_u, cur_i);
    fill_csr_kernel<<<(NE + 255) / 256, 256, 0, stream>>>(ei, cur_u, cur_i, csr_u, csr_i);

    const int GA_I = (NI * 64 + 255) / 256;   // items: one wave per node
    const int GA_U = (NU * 64 + 255) / 256;
    const int GB_I = (NI + 31) / 32;          // 8 nodes/wave * 4 waves
    const int GB_U = (NU + 31) / 32;

    // ---- layer 0 ----
    gatherA_kernel<<<GA_I, 256, 0, stream>>>(NI, item_emb, user_emb, rp_i, csr_i,
                                             rsd_i, rsd_u, acbuf, swbuf);
    transformB_kernel<<<GB_I, 256, 0, stream>>>(NI, acbuf, swbuf, rp_i,
                                                W1_0, b1_0, W2_0, b2_0, i1);
    gatherA_kernel<<<GA_U, 256, 0, stream>>>(NU, user_emb, item_emb, rp_u, csr_u,
                                             rsd_u, rsd_i, acbuf, swbuf);
    transformB_kernel<<<GB_U, 256, 0, stream>>>(NU, acbuf, swbuf, rp_u,
                                                W1_0, b1_0, W2_0, b2_0, u1);

    // ---- layer 1 ----
    gatherA_kernel<<<GA_I, 256, 0, stream>>>(NI, i1, u1, rp_i, csr_i,
                                             rsd_i, rsd_u, acbuf, swbuf);
    transformB_kernel<<<GB_I, 256, 0, stream>>>(NI, acbuf, swbuf, rp_i,
                                                W1_1, b1_1, W2_1, b2_1, i2);
    gatherA_kernel<<<GA_U, 256, 0, stream>>>(NU, u1, i1, rp_u, csr_u,
                                             rsd_u, rsd_i, acbuf, swbuf);
    transformB_kernel<<<GB_U, 256, 0, stream>>>(NU, acbuf, swbuf, rp_u,
                                                W1_1, b1_1, W2_1, b2_1, u2);

    // ---- final gather ----
    gather_kernel<<<(3 * NB * 48 + 255) / 256, 256, 0, stream>>>(
        user_emb, u1, u2, item_emb, i1, i2, users, pos, neg, (float4*)d_out);
}

// Round 9
// 800.103 us; speedup vs baseline: 1.1474x; 1.1474x over previous
//
#include <hip/hip_runtime.h>

#define NU 100000
#define NI 50000
#define NE 1000000
#define NB 16384

#define UB ((NU + 1023) / 1024)   // 98 user scan blocks
#define IB ((NI + 1023) / 1024)   // 49 item scan blocks

#define NBKT_I ((NI + 127) >> 7)   // 391 item buckets (128 nodes each)
#define NBKT_U ((NU + 255) >> 8)   // 391 user buckets (256 nodes each)
#define EPB 2048                   // edges per binP1 block

// ---- degree count (int atomics) ----
__global__ void deg_kernel(const int* __restrict__ ei, int* du, int* di) {
    int e = blockIdx.x * blockDim.x + threadIdx.x;
    if (e >= NE) return;
    atomicAdd(&du[ei[e]], 1);
    atomicAdd(&di[ei[NE + e]], 1);
}

// ---- scan pass 1: per-block partial sums (+ fused rsd computation) ----
__global__ __launch_bounds__(1024) void scan1_kernel(
        const int* __restrict__ du, const int* __restrict__ di,
        int* __restrict__ psum, float* __restrict__ rsd_u, float* __restrict__ rsd_i) {
    int b = blockIdx.x, tid = threadIdx.x;
    int v = 0;
    if (b < UB) {
        int i = b * 1024 + tid;
        if (i < NU) {
            int d = du[i]; v = d;
            rsd_u[i] = d > 0 ? 1.0f / sqrtf((float)d) : 0.f;
        }
    } else {
        int i = (b - UB) * 1024 + tid;
        if (i < NI) {
            int d = di[i]; v = d;
            rsd_i[i] = d > 0 ? 1.0f / sqrtf((float)d) : 0.f;
        }
    }
    int s = v;
    #pragma unroll
    for (int off = 32; off > 0; off >>= 1) s += __shfl_xor(s, off);
    __shared__ int ws[16];
    if ((tid & 63) == 0) ws[tid >> 6] = s;
    __syncthreads();
    if (tid == 0) {
        int t = 0;
        #pragma unroll
        for (int w = 0; w < 16; ++w) t += ws[w];
        psum[b] = t;
    }
}

// ---- scan pass 2: exclusive scan of block partials (per segment) ----
__global__ __launch_bounds__(128) void scan2_kernel(int* __restrict__ psum) {
    int base = (blockIdx.x == 0) ? 0 : UB;
    int n = (blockIdx.x == 0) ? UB : IB;
    int tid = threadIdx.x;
    __shared__ int sh[128];
    int v = (tid < n) ? psum[base + tid] : 0;
    sh[tid] = v;
    __syncthreads();
    for (int off = 1; off < 128; off <<= 1) {
        int t = (tid >= off) ? sh[tid - off] : 0;
        __syncthreads();
        sh[tid] += t;
        __syncthreads();
    }
    if (tid < n) psum[base + tid] = sh[tid] - v;  // exclusive
}

// ---- scan pass 3: block-local scan -> rowptr + bucket cursors ----
__global__ __launch_bounds__(1024) void scan3_kernel(
        const int* __restrict__ du, const int* __restrict__ di,
        const int* __restrict__ psum,
        int* __restrict__ rp_u, int* __restrict__ rp_i,
        int* __restrict__ bcur_u, int* __restrict__ bcur_i) {
    int b = blockIdx.x, tid = threadIdx.x;
    bool isU = (b < UB);
    const int* deg = isU ? du : di;
    int* rp = isU ? rp_u : rp_i;
    int N = isU ? NU : NI;
    int i0 = isU ? b * 1024 : (b - UB) * 1024;
    int i = i0 + tid;
    int v = (i < N) ? deg[i] : 0;
    __shared__ int sh[1024];
    sh[tid] = v;
    __syncthreads();
    for (int off = 1; off < 1024; off <<= 1) {
        int t = (tid >= off) ? sh[tid - off] : 0;
        __syncthreads();
        sh[tid] += t;
        __syncthreads();
    }
    int excl = sh[tid] - v + psum[b];
    if (i < N) {
        rp[i] = excl;
        if (isU) { if ((i & 255) == 0) bcur_u[i >> 8] = excl; }
        else     { if ((i & 127) == 0) bcur_i[i >> 7] = excl; }
    }
    if (b == 0 && tid == 0) { rp_u[NU] = NE; rp_i[NI] = NE; }
}

// ---- binP1: bucket-sort edges by item-dst and user-src (sequential writes) ----
__global__ __launch_bounds__(256) void binP1_kernel(
        const int* __restrict__ ei,
        int* __restrict__ bcur_i, int* __restrict__ bcur_u,
        int2* __restrict__ pairI, int2* __restrict__ pairU) {
    __shared__ int histA[NBKT_I], baseA[NBKT_I];
    __shared__ int histB[NBKT_U], baseB[NBKT_U];
    int t = threadIdx.x;
    int e0 = blockIdx.x * EPB;
    int cnt = min(EPB, NE - e0);
    int s[8], d[8];
    #pragma unroll
    for (int k = 0; k < 8; ++k) {
        int o = t + k * 256;
        if (o < cnt) { s[k] = ei[e0 + o]; d[k] = ei[NE + e0 + o]; }
        else { s[k] = -1; d[k] = -1; }
    }
    for (int x = t; x < NBKT_I; x += 256) histA[x] = 0;
    for (int x = t; x < NBKT_U; x += 256) histB[x] = 0;
    __syncthreads();
    #pragma unroll
    for (int k = 0; k < 8; ++k) {
        if (d[k] >= 0) {
            atomicAdd(&histA[d[k] >> 7], 1);
            atomicAdd(&histB[s[k] >> 8], 1);
        }
    }
    __syncthreads();
    for (int x = t; x < NBKT_I; x += 256) {
        int h = histA[x];
        baseA[x] = h ? atomicAdd(&bcur_i[x], h) : 0;
        histA[x] = 0;
    }
    for (int x = t; x < NBKT_U; x += 256) {
        int h = histB[x];
        baseB[x] = h ? atomicAdd(&bcur_u[x], h) : 0;
        histB[x] = 0;
    }
    __syncthreads();
    #pragma unroll
    for (int k = 0; k < 8; ++k) {
        if (d[k] >= 0) {
            int bI = d[k] >> 7;
            int off = atomicAdd(&histA[bI], 1);
            pairI[baseA[bI] + off] = make_int2(d[k], s[k]);
            int bU = s[k] >> 8;
            int off2 = atomicAdd(&histB[bU], 1);
            pairU[baseB[bU] + off2] = make_int2(s[k], d[k]);
        }
    }
}

// ---- binP2: one block per bucket, local CSR fill + rsd packing ----
// Scatter confined to the bucket's ~10-20KB window from a single block/XCD
// -> L2-absorbed (fill_csr's 130MB write-amp was cross-XCD 4B scatter).
__global__ __launch_bounds__(256) void binP2_kernel(
        const int2* __restrict__ pairI, const int2* __restrict__ pairU,
        const int* __restrict__ rp_i, const int* __restrict__ rp_u,
        const float* __restrict__ rsd_u, const float* __restrict__ rsd_i,
        int2* __restrict__ csr8_i, int2* __restrict__ csr8_u) {
    __shared__ int cur[256];
    int t = threadIdx.x;
    if (blockIdx.x < NBKT_I) {
        int b = blockIdx.x;
        int nb = b << 7, ne = min(nb + 128, NI);
        if (t < ne - nb) cur[t] = rp_i[nb + t];
        int wbeg = rp_i[nb], wend = rp_i[ne];
        __syncthreads();
        for (int j = wbeg + t; j < wend; j += 256) {
            int2 p = pairI[j];
            int slot = atomicAdd(&cur[p.x - nb], 1);
            csr8_i[slot] = make_int2(p.y, __float_as_int(rsd_u[p.y]));
        }
    } else {
        int b = blockIdx.x - NBKT_I;
        int nb = b << 8, ne = min(nb + 256, NU);
        if (t < ne - nb) cur[t] = rp_u[nb + t];
        int wbeg = rp_u[nb], wend = rp_u[ne];
        __syncthreads();
        for (int j = wbeg + t; j < wend; j += 256) {
            int2 p = pairU[j];
            int slot = atomicAdd(&cur[p.x - nb], 1);
            csr8_u[slot] = make_int2(p.y, __float_as_int(rsd_i[p.y]));
        }
    }
}

// ---- gather (both directions): one wave per node, no LDS ----
// csr8 entries are (nbr, rsd) -> coalesced 8B loads, no random rsd gather.
__global__ __launch_bounds__(256) void gatherA_kernel(
        const float* __restrict__ xu, const float* __restrict__ xi,
        const int* __restrict__ rp_u, const int* __restrict__ rp_i,
        const int2* __restrict__ csr8_u, const int2* __restrict__ csr8_i,
        const float* __restrict__ rsd_u, const float* __restrict__ rsd_i,
        float* __restrict__ acbuf_u, float* __restrict__ acbuf_i,
        float* __restrict__ swbuf_u, float* __restrict__ swbuf_i) {
    int n = (blockIdx.x * blockDim.x + threadIdx.x) >> 6;
    int lane = threadIdx.x & 63;
    if (n >= NI + NU) return;
    bool isItem = n < NI;
    int nn = isItem ? n : n - NI;
    const int* rp = isItem ? rp_i : rp_u;
    const int2* cs = isItem ? csr8_i : csr8_u;
    const float* x_own = isItem ? xi : xu;
    const float* emb_o = isItem ? xu : xi;
    float rs = isItem ? rsd_i[nn] : rsd_u[nn];
    float* acbuf = isItem ? acbuf_i : acbuf_u;
    float* swbuf = isItem ? swbuf_i : swbuf_u;

    int beg = rp[nn], end = rp[nn + 1];
    float sp = 0.f, ss = 0.f, swp = 0.f;
    for (int jj = beg; jj < end; jj += 64) {
        int m = min(64, end - jj);
        int2 rec = (lane < m) ? cs[jj + lane] : make_int2(0, 0);
        int idx = rec.x;
        float w = __int_as_float(rec.y);
        swp += w;
        int t = 0;
        for (; t + 3 < m; t += 4) {
            int s0 = __shfl(idx, t),     s1 = __shfl(idx, t + 1);
            int s2 = __shfl(idx, t + 2), s3 = __shfl(idx, t + 3);
            float w0 = __shfl(w, t),     w1 = __shfl(w, t + 1);
            float w2 = __shfl(w, t + 2), w3 = __shfl(w, t + 3);
            float v0 = emb_o[(size_t)s0 * 64 + lane];
            float v1 = emb_o[(size_t)s1 * 64 + lane];
            float v2 = emb_o[(size_t)s2 * 64 + lane];
            float v3 = emb_o[(size_t)s3 * 64 + lane];
            sp += (v0 + v1) + (v2 + v3);
            ss += w0 * v0 + w1 * v1 + w2 * v2 + w3 * v3;
        }
        for (; t < m; ++t) {
            int s0 = __shfl(idx, t);
            float w0 = __shfl(w, t);
            float v0 = emb_o[(size_t)s0 * 64 + lane];
            sp += v0; ss += w0 * v0;
        }
    }
    #pragma unroll
    for (int off = 32; off > 0; off >>= 1) swp += __shfl_xor(swp, off);
    acbuf[(size_t)nn * 128 + lane] = rs * ss;
    acbuf[(size_t)nn * 128 + 64 + lane] = x_own[(size_t)nn * 64 + lane] * sp;
    if (lane == 0) swbuf[nn] = rs * swp;
}

// ---- transform: 8 nodes per wave, W in 32KB LDS ----
#define TB 8
__global__ __launch_bounds__(256) void transformB_kernel(
        int N, const float* __restrict__ acbuf, const float* __restrict__ swbuf,
        const int* __restrict__ rp,
        const float* __restrict__ W1, const float* __restrict__ b1,
        const float* __restrict__ W2, const float* __restrict__ b2,
        float* __restrict__ out) {
    __shared__ float w1s[4096];
    __shared__ float w2s[4096];
    int tid = threadIdx.x;
    #pragma unroll
    for (int r = 0; r < 4; ++r) {
        *(float4*)&w1s[(r * 256 + tid) * 4] = *(const float4*)&W1[(r * 256 + tid) * 4];
        *(float4*)&w2s[(r * 256 + tid) * 4] = *(const float4*)&W2[(r * 256 + tid) * 4];
    }
    __syncthreads();
    int wv = tid >> 6, lane = tid & 63;
    int n0 = (blockIdx.x * 4 + wv) * TB;
    if (n0 >= N) return;
    float b1v = b1[lane], b2v = b2[lane];
    float acc[TB] = {0.f, 0.f, 0.f, 0.f, 0.f, 0.f, 0.f, 0.f};
    for (int kq = 0; kq < 16; ++kq) {
        float4 aq[TB], cq[TB];
        #pragma unroll
        for (int j = 0; j < TB; ++j) {
            int n = n0 + j; if (n >= N) n = N - 1;
            aq[j] = *(const float4*)&acbuf[(size_t)n * 128 + kq * 4];        // broadcast
            cq[j] = *(const float4*)&acbuf[(size_t)n * 128 + 64 + kq * 4];   // broadcast
        }
        #pragma unroll
        for (int kk = 0; kk < 4; ++kk) {
            int k = kq * 4 + kk;
            float w1v = w1s[k * 64 + lane];
            float w2v = w2s[k * 64 + lane];
            #pragma unroll
            for (int j = 0; j < TB; ++j)
                acc[j] += (&aq[j].x)[kk] * w1v + (&cq[j].x)[kk] * w2v;
        }
    }
    #pragma unroll
    for (int j = 0; j < TB; ++j) {
        int n = n0 + j;
        if (n >= N) break;
        float dgf = (float)(rp[n + 1] - rp[n]);
        float h = acc[j] + swbuf[n] * b1v + dgf * b2v;
        h = h >= 0.f ? h : 0.2f * h;
        float nsq = h * h;
        #pragma unroll
        for (int off = 32; off > 0; off >>= 1) nsq += __shfl_xor(nsq, off);
        float nrm = sqrtf(nsq);
        out[(size_t)n * 64 + lane] = h / fmaxf(nrm, 1e-12f);
    }
}

// ---- final gather of concatenated embeddings (float4) ----
__global__ void gather_kernel(const float* __restrict__ ue, const float* __restrict__ u1,
                              const float* __restrict__ u2, const float* __restrict__ ie,
                              const float* __restrict__ i1, const float* __restrict__ i2,
                              const int* __restrict__ users, const int* __restrict__ pos,
                              const int* __restrict__ neg, float4* __restrict__ out) {
    int idx = blockIdx.x * blockDim.x + threadIdx.x;     // float4 index
    if (idx >= 3 * NB * 48) return;
    int which = idx / (NB * 48);
    int rem = idx - which * (NB * 48);
    int b = rem / 48, c4 = rem - b * 48;                 // c4 in [0,48)
    int seg = c4 >> 4, cc = (c4 & 15) << 2;
    int row;
    const float* srcarr;
    if (which == 0) {
        row = users[b];
        srcarr = (seg == 0) ? ue : (seg == 1 ? u1 : u2);
    } else {
        row = (which == 1) ? pos[b] : neg[b];
        srcarr = (seg == 0) ? ie : (seg == 1 ? i1 : i2);
    }
    out[idx] = *(const float4*)&srcarr[(size_t)row * 64 + cc];
}

extern "C" void kernel_launch(void* const* d_in, const int* in_sizes, int n_in,
                              void* d_out, int out_size, void* d_ws, size_t ws_size,
                              hipStream_t stream) {
    const float* user_emb = (const float*)d_in[0];
    const float* item_emb = (const float*)d_in[1];
    const float* W1_0 = (const float*)d_in[2];
    const float* b1_0 = (const float*)d_in[3];
    const float* W2_0 = (const float*)d_in[4];
    const float* b2_0 = (const float*)d_in[5];
    const float* W1_1 = (const float*)d_in[6];
    const float* b1_1 = (const float*)d_in[7];
    const float* W2_1 = (const float*)d_in[8];
    const float* b2_1 = (const float*)d_in[9];
    const int* ei = (const int*)d_in[10];
    const int* users = (const int*)d_in[11];
    const int* pos = (const int*)d_in[12];
    const int* neg = (const int*)d_in[13];

    char* p = (char*)d_ws;
    int* du = (int*)p;          p += NU * 4;
    int* di = (int*)p;          p += NI * 4;
    float* rsd_u = (float*)p;   p += NU * 4;
    float* rsd_i = (float*)p;   p += NI * 4;
    int* psum = (int*)p;        p += (UB + IB) * 4;
    int* rp_u = (int*)p;        p += (NU + 1) * 4;
    int* rp_i = (int*)p;        p += (NI + 1) * 4;
    int* bcur_i = (int*)p;      p += NBKT_I * 4;
    int* bcur_u = (int*)p;      p += NBKT_U * 4;
    int2* csr8_u = (int2*)p;    p += (size_t)NE * 8;
    int2* csr8_i = (int2*)p;    p += (size_t)NE * 8;
    float* u1 = (float*)p;      p += (size_t)NU * 64 * 4;
    float* u2 = (float*)p;      p += (size_t)NU * 64 * 4;
    float* i1 = (float*)p;      p += (size_t)NI * 64 * 4;
    float* i2 = (float*)p;      p += (size_t)NI * 64 * 4;
    float* acbuf_u = (float*)p; p += (size_t)NU * 128 * 4;
    float* swbuf_u = (float*)p; p += NU * 4;
    float* swbuf_i = (float*)p; p += NI * 4;
    // aliases (dead-range proven):
    float* acbuf_i = u2;                 // acbuf_i dead before u2 is written
    int2* pairI = (int2*)acbuf_u;        // pair arrays dead before acbuf_u written
    int2* pairU = (int2*)(acbuf_u + (size_t)NE * 2);

    // zero the degree counters (ws is re-poisoned before every call)
    hipMemsetAsync(du, 0, (size_t)(NU + NI) * sizeof(int), stream);

    deg_kernel<<<(NE + 255) / 256, 256, 0, stream>>>(ei, du, di);
    scan1_kernel<<<UB + IB, 1024, 0, stream>>>(du, di, psum, rsd_u, rsd_i);
    scan2_kernel<<<2, 128, 0, stream>>>(psum);
    scan3_kernel<<<UB + IB, 1024, 0, stream>>>(du, di, psum, rp_u, rp_i, bcur_u, bcur_i);
    binP1_kernel<<<(NE + EPB - 1) / EPB, 256, 0, stream>>>(ei, bcur_i, bcur_u, pairI, pairU);
    binP2_kernel<<<NBKT_I + NBKT_U, 256, 0, stream>>>(pairI, pairU, rp_i, rp_u,
                                                      rsd_u, rsd_i, csr8_i, csr8_u);

    const int GA = ((NI + NU) * 64 + 255) / 256;
    const int GB_I = (NI + 4 * TB - 1) / (4 * TB);
    const int GB_U = (NU + 4 * TB - 1) / (4 * TB);

    // ---- layer 0 ----
    gatherA_kernel<<<GA, 256, 0, stream>>>(user_emb, item_emb, rp_u, rp_i, csr8_u, csr8_i,
                                           rsd_u, rsd_i, acbuf_u, acbuf_i, swbuf_u, swbuf_i);
    transformB_kernel<<<GB_I, 256, 0, stream>>>(NI, acbuf_i, swbuf_i, rp_i,
                                                W1_0, b1_0, W2_0, b2_0, i1);
    transformB_kernel<<<GB_U, 256, 0, stream>>>(NU, acbuf_u, swbuf_u, rp_u,
                                                W1_0, b1_0, W2_0, b2_0, u1);
    // ---- layer 1 ----
    gatherA_kernel<<<GA, 256, 0, stream>>>(u1, i1, rp_u, rp_i, csr8_u, csr8_i,
                                           rsd_u, rsd_i, acbuf_u, acbuf_i, swbuf_u, swbuf_i);
    transformB_kernel<<<GB_I, 256, 0, stream>>>(NI, acbuf_i, swbuf_i, rp_i,
                                                W1_1, b1_1, W2_1, b2_1, i2);
    transformB_kernel<<<GB_U, 256, 0, stream>>>(NU, acbuf_u, swbuf_u, rp_u,
                                                W1_1, b1_1, W2_1, b2_1, u2);

    // ---- final gather ----
    gather_kernel<<<(3 * NB * 48 + 255) / 256, 256, 0, stream>>>(
        user_emb, u1, u2, item_emb, i1, i2, users, pos, neg, (float4*)d_out);
}

// Round 10
// 656.151 us; speedup vs baseline: 1.3991x; 1.2194x over previous
//
#include <hip/hip_runtime.h>

#define NU 100000
#define NI 50000
#define NE 1000000
#define NB 16384

#define UB ((NU + 1023) / 1024)   // 98 user scan blocks
#define IB ((NI + 1023) / 1024)   // 49 item scan blocks

#define NBKT_I ((NI + 127) >> 7)   // 391 item buckets (128 nodes each)
#define NBKT_U ((NU + 255) >> 8)   // 391 user buckets (256 nodes each)
#define EPB 2048                   // edges per binP1 block

// ---- degree count (int atomics) ----
__global__ void deg_kernel(const int* __restrict__ ei, int* du, int* di) {
    int e = blockIdx.x * blockDim.x + threadIdx.x;
    if (e >= NE) return;
    atomicAdd(&du[ei[e]], 1);
    atomicAdd(&di[ei[NE + e]], 1);
}

// ---- scan pass 1: per-block partial sums (+ fused rsd computation) ----
__global__ __launch_bounds__(1024) void scan1_kernel(
        const int* __restrict__ du, const int* __restrict__ di,
        int* __restrict__ psum, float* __restrict__ rsd_u, float* __restrict__ rsd_i) {
    int b = blockIdx.x, tid = threadIdx.x;
    int v = 0;
    if (b < UB) {
        int i = b * 1024 + tid;
        if (i < NU) {
            int d = du[i]; v = d;
            rsd_u[i] = d > 0 ? 1.0f / sqrtf((float)d) : 0.f;
        }
    } else {
        int i = (b - UB) * 1024 + tid;
        if (i < NI) {
            int d = di[i]; v = d;
            rsd_i[i] = d > 0 ? 1.0f / sqrtf((float)d) : 0.f;
        }
    }
    int s = v;
    #pragma unroll
    for (int off = 32; off > 0; off >>= 1) s += __shfl_xor(s, off);
    __shared__ int ws[16];
    if ((tid & 63) == 0) ws[tid >> 6] = s;
    __syncthreads();
    if (tid == 0) {
        int t = 0;
        #pragma unroll
        for (int w = 0; w < 16; ++w) t += ws[w];
        psum[b] = t;
    }
}

// ---- scan pass 2: exclusive scan of block partials (per segment) ----
__global__ __launch_bounds__(128) void scan2_kernel(int* __restrict__ psum) {
    int base = (blockIdx.x == 0) ? 0 : UB;
    int n = (blockIdx.x == 0) ? UB : IB;
    int tid = threadIdx.x;
    __shared__ int sh[128];
    int v = (tid < n) ? psum[base + tid] : 0;
    sh[tid] = v;
    __syncthreads();
    for (int off = 1; off < 128; off <<= 1) {
        int t = (tid >= off) ? sh[tid - off] : 0;
        __syncthreads();
        sh[tid] += t;
        __syncthreads();
    }
    if (tid < n) psum[base + tid] = sh[tid] - v;  // exclusive
}

// ---- scan pass 3: block-local scan -> rowptr + bucket cursors ----
__global__ __launch_bounds__(1024) void scan3_kernel(
        const int* __restrict__ du, const int* __restrict__ di,
        const int* __restrict__ psum,
        int* __restrict__ rp_u, int* __restrict__ rp_i,
        int* __restrict__ bcur_u, int* __restrict__ bcur_i) {
    int b = blockIdx.x, tid = threadIdx.x;
    bool isU = (b < UB);
    const int* deg = isU ? du : di;
    int* rp = isU ? rp_u : rp_i;
    int N = isU ? NU : NI;
    int i0 = isU ? b * 1024 : (b - UB) * 1024;
    int i = i0 + tid;
    int v = (i < N) ? deg[i] : 0;
    __shared__ int sh[1024];
    sh[tid] = v;
    __syncthreads();
    for (int off = 1; off < 1024; off <<= 1) {
        int t = (tid >= off) ? sh[tid - off] : 0;
        __syncthreads();
        sh[tid] += t;
        __syncthreads();
    }
    int excl = sh[tid] - v + psum[b];
    if (i < N) {
        rp[i] = excl;
        if (isU) { if ((i & 255) == 0) bcur_u[i >> 8] = excl; }
        else     { if ((i & 127) == 0) bcur_i[i >> 7] = excl; }
    }
    if (b == 0 && tid == 0) { rp_u[NU] = NE; rp_i[NI] = NE; }
}

// ---- binP1: bucket-sort edges by item-dst and user-src (sequential writes) ----
__global__ __launch_bounds__(256) void binP1_kernel(
        const int* __restrict__ ei,
        int* __restrict__ bcur_i, int* __restrict__ bcur_u,
        int2* __restrict__ pairI, int2* __restrict__ pairU) {
    __shared__ int histA[NBKT_I], baseA[NBKT_I];
    __shared__ int histB[NBKT_U], baseB[NBKT_U];
    int t = threadIdx.x;
    int e0 = blockIdx.x * EPB;
    int cnt = min(EPB, NE - e0);
    int s[8], d[8];
    #pragma unroll
    for (int k = 0; k < 8; ++k) {
        int o = t + k * 256;
        if (o < cnt) { s[k] = ei[e0 + o]; d[k] = ei[NE + e0 + o]; }
        else { s[k] = -1; d[k] = -1; }
    }
    for (int x = t; x < NBKT_I; x += 256) histA[x] = 0;
    for (int x = t; x < NBKT_U; x += 256) histB[x] = 0;
    __syncthreads();
    #pragma unroll
    for (int k = 0; k < 8; ++k) {
        if (d[k] >= 0) {
            atomicAdd(&histA[d[k] >> 7], 1);
            atomicAdd(&histB[s[k] >> 8], 1);
        }
    }
    __syncthreads();
    for (int x = t; x < NBKT_I; x += 256) {
        int h = histA[x];
        baseA[x] = h ? atomicAdd(&bcur_i[x], h) : 0;
        histA[x] = 0;
    }
    for (int x = t; x < NBKT_U; x += 256) {
        int h = histB[x];
        baseB[x] = h ? atomicAdd(&bcur_u[x], h) : 0;
        histB[x] = 0;
    }
    __syncthreads();
    #pragma unroll
    for (int k = 0; k < 8; ++k) {
        if (d[k] >= 0) {
            int bI = d[k] >> 7;
            int off = atomicAdd(&histA[bI], 1);
            pairI[baseA[bI] + off] = make_int2(d[k], s[k]);
            int bU = s[k] >> 8;
            int off2 = atomicAdd(&histB[bU], 1);
            pairU[baseB[bU] + off2] = make_int2(s[k], d[k]);
        }
    }
}

// ---- binP2: one block per bucket, local CSR fill + rsd packing ----
__global__ __launch_bounds__(256) void binP2_kernel(
        const int2* __restrict__ pairI, const int2* __restrict__ pairU,
        const int* __restrict__ rp_i, const int* __restrict__ rp_u,
        const float* __restrict__ rsd_u, const float* __restrict__ rsd_i,
        int2* __restrict__ csr8_i, int2* __restrict__ csr8_u) {
    __shared__ int cur[256];
    int t = threadIdx.x;
    if (blockIdx.x < NBKT_I) {
        int b = blockIdx.x;
        int nb = b << 7, ne = min(nb + 128, NI);
        if (t < ne - nb) cur[t] = rp_i[nb + t];
        int wbeg = rp_i[nb], wend = rp_i[ne];
        __syncthreads();
        for (int j = wbeg + t; j < wend; j += 256) {
            int2 p = pairI[j];
            int slot = atomicAdd(&cur[p.x - nb], 1);
            csr8_i[slot] = make_int2(p.y, __float_as_int(rsd_u[p.y]));
        }
    } else {
        int b = blockIdx.x - NBKT_I;
        int nb = b << 8, ne = min(nb + 256, NU);
        if (t < ne - nb) cur[t] = rp_u[nb + t];
        int wbeg = rp_u[nb], wend = rp_u[ne];
        __syncthreads();
        for (int j = wbeg + t; j < wend; j += 256) {
            int2 p = pairU[j];
            int slot = atomicAdd(&cur[p.x - nb], 1);
            csr8_u[slot] = make_int2(p.y, __float_as_int(rsd_i[p.y]));
        }
    }
}

// ---- gather (both directions): one wave per node, no LDS ----
__global__ __launch_bounds__(256) void gatherA_kernel(
        const float* __restrict__ xu, const float* __restrict__ xi,
        const int* __restrict__ rp_u, const int* __restrict__ rp_i,
        const int2* __restrict__ csr8_u, const int2* __restrict__ csr8_i,
        const float* __restrict__ rsd_u, const float* __restrict__ rsd_i,
        float* __restrict__ acbuf_u, float* __restrict__ acbuf_i,
        float* __restrict__ swbuf_u, float* __restrict__ swbuf_i) {
    int n = (blockIdx.x * blockDim.x + threadIdx.x) >> 6;
    int lane = threadIdx.x & 63;
    if (n >= NI + NU) return;
    bool isItem = n < NI;
    int nn = isItem ? n : n - NI;
    const int* rp = isItem ? rp_i : rp_u;
    const int2* cs = isItem ? csr8_i : csr8_u;
    const float* x_own = isItem ? xi : xu;
    const float* emb_o = isItem ? xu : xi;
    float rs = isItem ? rsd_i[nn] : rsd_u[nn];
    float* acbuf = isItem ? acbuf_i : acbuf_u;
    float* swbuf = isItem ? swbuf_i : swbuf_u;

    int beg = rp[nn], end = rp[nn + 1];
    float sp = 0.f, ss = 0.f, swp = 0.f;
    for (int jj = beg; jj < end; jj += 64) {
        int m = min(64, end - jj);
        int2 rec = (lane < m) ? cs[jj + lane] : make_int2(0, 0);
        int idx = rec.x;
        float w = __int_as_float(rec.y);
        swp += w;
        int t = 0;
        for (; t + 3 < m; t += 4) {
            int s0 = __shfl(idx, t),     s1 = __shfl(idx, t + 1);
            int s2 = __shfl(idx, t + 2), s3 = __shfl(idx, t + 3);
            float w0 = __shfl(w, t),     w1 = __shfl(w, t + 1);
            float w2 = __shfl(w, t + 2), w3 = __shfl(w, t + 3);
            float v0 = emb_o[(size_t)s0 * 64 + lane];
            float v1 = emb_o[(size_t)s1 * 64 + lane];
            float v2 = emb_o[(size_t)s2 * 64 + lane];
            float v3 = emb_o[(size_t)s3 * 64 + lane];
            sp += (v0 + v1) + (v2 + v3);
            ss += w0 * v0 + w1 * v1 + w2 * v2 + w3 * v3;
        }
        for (; t < m; ++t) {
            int s0 = __shfl(idx, t);
            float w0 = __shfl(w, t);
            float v0 = emb_o[(size_t)s0 * 64 + lane];
            sp += v0; ss += w0 * v0;
        }
    }
    #pragma unroll
    for (int off = 32; off > 0; off >>= 1) swp += __shfl_xor(swp, off);
    acbuf[(size_t)nn * 128 + lane] = rs * ss;
    acbuf[(size_t)nn * 128 + 64 + lane] = x_own[(size_t)nn * 64 + lane] * sp;
    if (lane == 0) swbuf[nn] = rs * swp;
}

// ---- transform: TB=4 nodes per wave; a/c staged coalesced into LDS, read
// back as broadcasts (R9's 256 uniform-address GLOBAL loads/wave at 37% occ
// were the latency bound). W in LDS verbatim k-major: stride-1, 0 conflicts.
#define TB 4
__global__ __launch_bounds__(256) void transformB_kernel(
        int N, const float* __restrict__ acbuf, const float* __restrict__ swbuf,
        const int* __restrict__ rp,
        const float* __restrict__ W1, const float* __restrict__ b1,
        const float* __restrict__ W2, const float* __restrict__ b2,
        float* __restrict__ out) {
    __shared__ float w1s[4096];
    __shared__ float w2s[4096];
    __shared__ float acs[4][TB * 128];    // 8 KB: per-wave 4-node a||c slabs
    int tid = threadIdx.x;
    #pragma unroll
    for (int r = 0; r < 4; ++r) {
        *(float4*)&w1s[(r * 256 + tid) * 4] = *(const float4*)&W1[(r * 256 + tid) * 4];
        *(float4*)&w2s[(r * 256 + tid) * 4] = *(const float4*)&W2[(r * 256 + tid) * 4];
    }
    __syncthreads();
    int wv = tid >> 6, lane = tid & 63;
    int n0 = (blockIdx.x * 4 + wv) * TB;
    if (n0 >= N) return;
    float* slab = acs[wv];
    // stage: 2 nodes per pass (lanes 0-31 node j, 32-63 node j+1), float4 each
    int half = lane >> 5;
    int off = (lane & 31) * 4;
    #pragma unroll
    for (int pr = 0; pr < 2; ++pr) {
        int j = pr * 2 + half;
        int n = n0 + j; if (n >= N) n = N - 1;
        *(float4*)&slab[j * 128 + off] = *(const float4*)&acbuf[(size_t)n * 128 + off];
    }
    float acc[TB] = {0.f, 0.f, 0.f, 0.f};
    #pragma unroll 4
    for (int kq = 0; kq < 16; ++kq) {
        float4 aq[TB], cq[TB];
        #pragma unroll
        for (int j = 0; j < TB; ++j) {
            aq[j] = *(const float4*)&slab[j * 128 + kq * 4];       // LDS broadcast
            cq[j] = *(const float4*)&slab[j * 128 + 64 + kq * 4];  // LDS broadcast
        }
        #pragma unroll
        for (int kk = 0; kk < 4; ++kk) {
            int k = kq * 4 + kk;
            float w1v = w1s[k * 64 + lane];
            float w2v = w2s[k * 64 + lane];
            #pragma unroll
            for (int j = 0; j < TB; ++j)
                acc[j] += (&aq[j].x)[kk] * w1v + (&cq[j].x)[kk] * w2v;
        }
    }
    float b1v = b1[lane], b2v = b2[lane];
    #pragma unroll
    for (int j = 0; j < TB; ++j) {
        int n = n0 + j;
        if (n >= N) break;
        float dgf = (float)(rp[n + 1] - rp[n]);
        float h = acc[j] + swbuf[n] * b1v + dgf * b2v;
        h = h >= 0.f ? h : 0.2f * h;
        float nsq = h * h;
        #pragma unroll
        for (int o = 32; o > 0; o >>= 1) nsq += __shfl_xor(nsq, o);
        float nrm = sqrtf(nsq);
        out[(size_t)n * 64 + lane] = h / fmaxf(nrm, 1e-12f);
    }
}

// ---- final gather of concatenated embeddings (float4) ----
__global__ void gather_kernel(const float* __restrict__ ue, const float* __restrict__ u1,
                              const float* __restrict__ u2, const float* __restrict__ ie,
                              const float* __restrict__ i1, const float* __restrict__ i2,
                              const int* __restrict__ users, const int* __restrict__ pos,
                              const int* __restrict__ neg, float4* __restrict__ out) {
    int idx = blockIdx.x * blockDim.x + threadIdx.x;     // float4 index
    if (idx >= 3 * NB * 48) return;
    int which = idx / (NB * 48);
    int rem = idx - which * (NB * 48);
    int b = rem / 48, c4 = rem - b * 48;                 // c4 in [0,48)
    int seg = c4 >> 4, cc = (c4 & 15) << 2;
    int row;
    const float* srcarr;
    if (which == 0) {
        row = users[b];
        srcarr = (seg == 0) ? ue : (seg == 1 ? u1 : u2);
    } else {
        row = (which == 1) ? pos[b] : neg[b];
        srcarr = (seg == 0) ? ie : (seg == 1 ? i1 : i2);
    }
    out[idx] = *(const float4*)&srcarr[(size_t)row * 64 + cc];
}

extern "C" void kernel_launch(void* const* d_in, const int* in_sizes, int n_in,
                              void* d_out, int out_size, void* d_ws, size_t ws_size,
                              hipStream_t stream) {
    const float* user_emb = (const float*)d_in[0];
    const float* item_emb = (const float*)d_in[1];
    const float* W1_0 = (const float*)d_in[2];
    const float* b1_0 = (const float*)d_in[3];
    const float* W2_0 = (const float*)d_in[4];
    const float* b2_0 = (const float*)d_in[5];
    const float* W1_1 = (const float*)d_in[6];
    const float* b1_1 = (const float*)d_in[7];
    const float* W2_1 = (const float*)d_in[8];
    const float* b2_1 = (const float*)d_in[9];
    const int* ei = (const int*)d_in[10];
    const int* users = (const int*)d_in[11];
    const int* pos = (const int*)d_in[12];
    const int* neg = (const int*)d_in[13];

    char* p = (char*)d_ws;
    int* du = (int*)p;          p += NU * 4;
    int* di = (int*)p;          p += NI * 4;
    float* rsd_u = (float*)p;   p += NU * 4;
    float* rsd_i = (float*)p;   p += NI * 4;
    int* psum = (int*)p;        p += (UB + IB) * 4;
    int* rp_u = (int*)p;        p += (NU + 1) * 4;
    int* rp_i = (int*)p;        p += (NI + 1) * 4;
    int* bcur_i = (int*)p;      p += NBKT_I * 4;
    int* bcur_u = (int*)p;      p += NBKT_U * 4;
    int2* csr8_u = (int2*)p;    p += (size_t)NE * 8;
    int2* csr8_i = (int2*)p;    p += (size_t)NE * 8;
    float* u1 = (float*)p;      p += (size_t)NU * 64 * 4;
    float* u2 = (float*)p;      p += (size_t)NU * 64 * 4;
    float* i1 = (float*)p;      p += (size_t)NI * 64 * 4;
    float* i2 = (float*)p;      p += (size_t)NI * 64 * 4;
    float* acbuf_u = (float*)p; p += (size_t)NU * 128 * 4;
    float* swbuf_u = (float*)p; p += NU * 4;
    float* swbuf_i = (float*)p; p += NI * 4;
    // aliases (dead-range proven):
    float* acbuf_i = u2;                 // item transform completes before u2 written
    int2* pairI = (int2*)acbuf_u;        // pair arrays dead before acbuf_u written
    int2* pairU = (int2*)(acbuf_u + (size_t)NE * 2);

    // zero the degree counters (ws is re-poisoned before every call)
    hipMemsetAsync(du, 0, (size_t)(NU + NI) * sizeof(int), stream);

    deg_kernel<<<(NE + 255) / 256, 256, 0, stream>>>(ei, du, di);
    scan1_kernel<<<UB + IB, 1024, 0, stream>>>(du, di, psum, rsd_u, rsd_i);
    scan2_kernel<<<2, 128, 0, stream>>>(psum);
    scan3_kernel<<<UB + IB, 1024, 0, stream>>>(du, di, psum, rp_u, rp_i, bcur_u, bcur_i);
    binP1_kernel<<<(NE + EPB - 1) / EPB, 256, 0, stream>>>(ei, bcur_i, bcur_u, pairI, pairU);
    binP2_kernel<<<NBKT_I + NBKT_U, 256, 0, stream>>>(pairI, pairU, rp_i, rp_u,
                                                      rsd_u, rsd_i, csr8_i, csr8_u);

    const int GA = ((NI + NU) * 64 + 255) / 256;
    const int GB_I = (NI + 4 * TB - 1) / (4 * TB);
    const int GB_U = (NU + 4 * TB - 1) / (4 * TB);

    // ---- layer 0 ----
    gatherA_kernel<<<GA, 256, 0, stream>>>(user_emb, item_emb, rp_u, rp_i, csr8_u, csr8_i,
                                           rsd_u, rsd_i, acbuf_u, acbuf_i, swbuf_u, swbuf_i);
    transformB_kernel<<<GB_I, 256, 0, stream>>>(NI, acbuf_i, swbuf_i, rp_i,
                                                W1_0, b1_0, W2_0, b2_0, i1);
    transformB_kernel<<<GB_U, 256, 0, stream>>>(NU, acbuf_u, swbuf_u, rp_u,
                                                W1_0, b1_0, W2_0, b2_0, u1);
    // ---- layer 1 ----
    gatherA_kernel<<<GA, 256, 0, stream>>>(u1, i1, rp_u, rp_i, csr8_u, csr8_i,
                                           rsd_u, rsd_i, acbuf_u, acbuf_i, swbuf_u, swbuf_i);
    transformB_kernel<<<GB_I, 256, 0, stream>>>(NI, acbuf_i, swbuf_i, rp_i,
                                                W1_1, b1_1, W2_1, b2_1, i2);
    transformB_kernel<<<GB_U, 256, 0, stream>>>(NU, acbuf_u, swbuf_u, rp_u,
                                                W1_1, b1_1, W2_1, b2_1, u2);

    // ---- final gather ----
    gather_kernel<<<(3 * NB * 48 + 255) / 256, 256, 0, stream>>>(
        user_emb, u1, u2, item_emb, i1, i2, users, pos, neg, (float4*)d_out);
}

// Round 11
// 636.693 us; speedup vs baseline: 1.4418x; 1.0306x over previous
//
#include <hip/hip_runtime.h>

#define NU 100000
#define NI 50000
#define NE 1000000
#define NB 16384

#define UB ((NU + 1023) / 1024)   // 98 user scan blocks
#define IB ((NI + 1023) / 1024)   // 49 item scan blocks

#define NBKT_I ((NI + 127) >> 7)   // 391 item buckets (128 nodes each)
#define NBKT_U ((NU + 255) >> 8)   // 391 user buckets (256 nodes each)
#define EPB 2048                   // edges per binP1 block

typedef unsigned short u16;
typedef unsigned int u32;

__device__ __forceinline__ u16 f2bf(float f) {        // RNE f32 -> bf16
    u32 u = __float_as_uint(f);
    u32 r = u + 0x7FFFu + ((u >> 16) & 1u);
    return (u16)(r >> 16);
}
__device__ __forceinline__ float bf2f(u16 s) {        // exact bf16 -> f32
    return __uint_as_float(((u32)s) << 16);
}

// ---- degree count (int atomics) ----
__global__ void deg_kernel(const int* __restrict__ ei, int* du, int* di) {
    int e = blockIdx.x * blockDim.x + threadIdx.x;
    if (e >= NE) return;
    atomicAdd(&du[ei[e]], 1);
    atomicAdd(&di[ei[NE + e]], 1);
}

// ---- bf16 copies of the initial embeddings ----
__global__ void convert_kernel(const float4* __restrict__ ue4, const float4* __restrict__ ie4,
                               ushort4* __restrict__ ueb4, ushort4* __restrict__ ieb4) {
    int i = blockIdx.x * blockDim.x + threadIdx.x;
    const int TU = NU * 16;
    if (i < TU) {
        float4 v = ue4[i];
        ushort4 r; r.x = f2bf(v.x); r.y = f2bf(v.y); r.z = f2bf(v.z); r.w = f2bf(v.w);
        ueb4[i] = r;
    } else if (i < TU + NI * 16) {
        int j = i - TU;
        float4 v = ie4[j];
        ushort4 r; r.x = f2bf(v.x); r.y = f2bf(v.y); r.z = f2bf(v.z); r.w = f2bf(v.w);
        ieb4[j] = r;
    }
}

// ---- scan pass 1: per-block partial sums (+ fused rsd computation) ----
__global__ __launch_bounds__(1024) void scan1_kernel(
        const int* __restrict__ du, const int* __restrict__ di,
        int* __restrict__ psum, float* __restrict__ rsd_u, float* __restrict__ rsd_i) {
    int b = blockIdx.x, tid = threadIdx.x;
    int v = 0;
    if (b < UB) {
        int i = b * 1024 + tid;
        if (i < NU) {
            int d = du[i]; v = d;
            rsd_u[i] = d > 0 ? 1.0f / sqrtf((float)d) : 0.f;
        }
    } else {
        int i = (b - UB) * 1024 + tid;
        if (i < NI) {
            int d = di[i]; v = d;
            rsd_i[i] = d > 0 ? 1.0f / sqrtf((float)d) : 0.f;
        }
    }
    int s = v;
    #pragma unroll
    for (int off = 32; off > 0; off >>= 1) s += __shfl_xor(s, off);
    __shared__ int ws[16];
    if ((tid & 63) == 0) ws[tid >> 6] = s;
    __syncthreads();
    if (tid == 0) {
        int t = 0;
        #pragma unroll
        for (int w = 0; w < 16; ++w) t += ws[w];
        psum[b] = t;
    }
}

// ---- scan pass 2: exclusive scan of block partials (per segment) ----
__global__ __launch_bounds__(128) void scan2_kernel(int* __restrict__ psum) {
    int base = (blockIdx.x == 0) ? 0 : UB;
    int n = (blockIdx.x == 0) ? UB : IB;
    int tid = threadIdx.x;
    __shared__ int sh[128];
    int v = (tid < n) ? psum[base + tid] : 0;
    sh[tid] = v;
    __syncthreads();
    for (int off = 1; off < 128; off <<= 1) {
        int t = (tid >= off) ? sh[tid - off] : 0;
        __syncthreads();
        sh[tid] += t;
        __syncthreads();
    }
    if (tid < n) psum[base + tid] = sh[tid] - v;  // exclusive
}

// ---- scan pass 3: block-local scan -> rowptr + bucket cursors ----
__global__ __launch_bounds__(1024) void scan3_kernel(
        const int* __restrict__ du, const int* __restrict__ di,
        const int* __restrict__ psum,
        int* __restrict__ rp_u, int* __restrict__ rp_i,
        int* __restrict__ bcur_u, int* __restrict__ bcur_i) {
    int b = blockIdx.x, tid = threadIdx.x;
    bool isU = (b < UB);
    const int* deg = isU ? du : di;
    int* rp = isU ? rp_u : rp_i;
    int N = isU ? NU : NI;
    int i0 = isU ? b * 1024 : (b - UB) * 1024;
    int i = i0 + tid;
    int v = (i < N) ? deg[i] : 0;
    __shared__ int sh[1024];
    sh[tid] = v;
    __syncthreads();
    for (int off = 1; off < 1024; off <<= 1) {
        int t = (tid >= off) ? sh[tid - off] : 0;
        __syncthreads();
        sh[tid] += t;
        __syncthreads();
    }
    int excl = sh[tid] - v + psum[b];
    if (i < N) {
        rp[i] = excl;
        if (isU) { if ((i & 255) == 0) bcur_u[i >> 8] = excl; }
        else     { if ((i & 127) == 0) bcur_i[i >> 7] = excl; }
    }
    if (b == 0 && tid == 0) { rp_u[NU] = NE; rp_i[NI] = NE; }
}

// ---- binP1: bucket-sort edges by item-dst and user-src (sequential writes) ----
__global__ __launch_bounds__(256) void binP1_kernel(
        const int* __restrict__ ei,
        int* __restrict__ bcur_i, int* __restrict__ bcur_u,
        int2* __restrict__ pairI, int2* __restrict__ pairU) {
    __shared__ int histA[NBKT_I], baseA[NBKT_I];
    __shared__ int histB[NBKT_U], baseB[NBKT_U];
    int t = threadIdx.x;
    int e0 = blockIdx.x * EPB;
    int cnt = min(EPB, NE - e0);
    int s[8], d[8];
    #pragma unroll
    for (int k = 0; k < 8; ++k) {
        int o = t + k * 256;
        if (o < cnt) { s[k] = ei[e0 + o]; d[k] = ei[NE + e0 + o]; }
        else { s[k] = -1; d[k] = -1; }
    }
    for (int x = t; x < NBKT_I; x += 256) histA[x] = 0;
    for (int x = t; x < NBKT_U; x += 256) histB[x] = 0;
    __syncthreads();
    #pragma unroll
    for (int k = 0; k < 8; ++k) {
        if (d[k] >= 0) {
            atomicAdd(&histA[d[k] >> 7], 1);
            atomicAdd(&histB[s[k] >> 8], 1);
        }
    }
    __syncthreads();
    for (int x = t; x < NBKT_I; x += 256) {
        int h = histA[x];
        baseA[x] = h ? atomicAdd(&bcur_i[x], h) : 0;
        histA[x] = 0;
    }
    for (int x = t; x < NBKT_U; x += 256) {
        int h = histB[x];
        baseB[x] = h ? atomicAdd(&bcur_u[x], h) : 0;
        histB[x] = 0;
    }
    __syncthreads();
    #pragma unroll
    for (int k = 0; k < 8; ++k) {
        if (d[k] >= 0) {
            int bI = d[k] >> 7;
            int off = atomicAdd(&histA[bI], 1);
            pairI[baseA[bI] + off] = make_int2(d[k], s[k]);
            int bU = s[k] >> 8;
            int off2 = atomicAdd(&histB[bU], 1);
            pairU[baseB[bU] + off2] = make_int2(s[k], d[k]);
        }
    }
}

// ---- binP2: one block per bucket, local CSR fill + rsd packing ----
__global__ __launch_bounds__(256) void binP2_kernel(
        const int2* __restrict__ pairI, const int2* __restrict__ pairU,
        const int* __restrict__ rp_i, const int* __restrict__ rp_u,
        const float* __restrict__ rsd_u, const float* __restrict__ rsd_i,
        int2* __restrict__ csr8_i, int2* __restrict__ csr8_u) {
    __shared__ int cur[256];
    int t = threadIdx.x;
    if (blockIdx.x < NBKT_I) {
        int b = blockIdx.x;
        int nb = b << 7, ne = min(nb + 128, NI);
        if (t < ne - nb) cur[t] = rp_i[nb + t];
        int wbeg = rp_i[nb], wend = rp_i[ne];
        __syncthreads();
        for (int j = wbeg + t; j < wend; j += 256) {
            int2 p = pairI[j];
            int slot = atomicAdd(&cur[p.x - nb], 1);
            csr8_i[slot] = make_int2(p.y, __float_as_int(rsd_u[p.y]));
        }
    } else {
        int b = blockIdx.x - NBKT_I;
        int nb = b << 8, ne = min(nb + 256, NU);
        if (t < ne - nb) cur[t] = rp_u[nb + t];
        int wbeg = rp_u[nb], wend = rp_u[ne];
        __syncthreads();
        for (int j = wbeg + t; j < wend; j += 256) {
            int2 p = pairU[j];
            int slot = atomicAdd(&cur[p.x - nb], 1);
            csr8_u[slot] = make_int2(p.y, __float_as_int(rsd_i[p.y]));
        }
    }
}

// ---- gather (both directions): one wave per node, no LDS ----
// Neighbor rows read from BF16 copies (128B/row, halves random-gather bytes);
// acbuf written bf16 (halves intermediate traffic). x_own stays f32.
__global__ __launch_bounds__(256) void gatherA_kernel(
        const float* __restrict__ xu, const float* __restrict__ xi,
        const u16* __restrict__ ub, const u16* __restrict__ ib,
        const int* __restrict__ rp_u, const int* __restrict__ rp_i,
        const int2* __restrict__ csr8_u, const int2* __restrict__ csr8_i,
        const float* __restrict__ rsd_u, const float* __restrict__ rsd_i,
        u16* __restrict__ acbuf_u, u16* __restrict__ acbuf_i,
        float* __restrict__ swbuf_u, float* __restrict__ swbuf_i) {
    int n = (blockIdx.x * blockDim.x + threadIdx.x) >> 6;
    int lane = threadIdx.x & 63;
    if (n >= NI + NU) return;
    bool isItem = n < NI;
    int nn = isItem ? n : n - NI;
    const int* rp = isItem ? rp_i : rp_u;
    const int2* cs = isItem ? csr8_i : csr8_u;
    const float* x_own = isItem ? xi : xu;
    const u16* emb_o = isItem ? ub : ib;          // item aggregates users, user aggregates items
    float rs = isItem ? rsd_i[nn] : rsd_u[nn];
    u16* acbuf = isItem ? acbuf_i : acbuf_u;
    float* swbuf = isItem ? swbuf_i : swbuf_u;

    int beg = rp[nn], end = rp[nn + 1];
    float sp = 0.f, ss = 0.f, swp = 0.f;
    for (int jj = beg; jj < end; jj += 64) {
        int m = min(64, end - jj);
        int2 rec = (lane < m) ? cs[jj + lane] : make_int2(0, 0);
        int idx = rec.x;
        float w = __int_as_float(rec.y);
        swp += w;
        int t = 0;
        for (; t + 3 < m; t += 4) {
            int s0 = __shfl(idx, t),     s1 = __shfl(idx, t + 1);
            int s2 = __shfl(idx, t + 2), s3 = __shfl(idx, t + 3);
            float w0 = __shfl(w, t),     w1 = __shfl(w, t + 1);
            float w2 = __shfl(w, t + 2), w3 = __shfl(w, t + 3);
            float v0 = bf2f(emb_o[(size_t)s0 * 64 + lane]);
            float v1 = bf2f(emb_o[(size_t)s1 * 64 + lane]);
            float v2 = bf2f(emb_o[(size_t)s2 * 64 + lane]);
            float v3 = bf2f(emb_o[(size_t)s3 * 64 + lane]);
            sp += (v0 + v1) + (v2 + v3);
            ss += w0 * v0 + w1 * v1 + w2 * v2 + w3 * v3;
        }
        for (; t < m; ++t) {
            int s0 = __shfl(idx, t);
            float w0 = __shfl(w, t);
            float v0 = bf2f(emb_o[(size_t)s0 * 64 + lane]);
            sp += v0; ss += w0 * v0;
        }
    }
    #pragma unroll
    for (int off = 32; off > 0; off >>= 1) swp += __shfl_xor(swp, off);
    acbuf[(size_t)nn * 128 + lane] = f2bf(rs * ss);
    acbuf[(size_t)nn * 128 + 64 + lane] = f2bf(x_own[(size_t)nn * 64 + lane] * sp);
    if (lane == 0) swbuf[nn] = rs * swp;
}

// ---- transform: TB=4 nodes per wave; bf16 acbuf staged->f32 LDS slab;
// W in LDS verbatim k-major (stride-1, 0 conflicts). Optional bf16 out copy.
#define TB 4
__global__ __launch_bounds__(256) void transformB_kernel(
        int N, const u16* __restrict__ acbuf, const float* __restrict__ swbuf,
        const int* __restrict__ rp,
        const float* __restrict__ W1, const float* __restrict__ b1,
        const float* __restrict__ W2, const float* __restrict__ b2,
        float* __restrict__ out, u16* __restrict__ outb) {
    __shared__ float w1s[4096];
    __shared__ float w2s[4096];
    __shared__ float acs[4][TB * 128];    // 8 KB: per-wave 4-node a||c slabs
    int tid = threadIdx.x;
    #pragma unroll
    for (int r = 0; r < 4; ++r) {
        *(float4*)&w1s[(r * 256 + tid) * 4] = *(const float4*)&W1[(r * 256 + tid) * 4];
        *(float4*)&w2s[(r * 256 + tid) * 4] = *(const float4*)&W2[(r * 256 + tid) * 4];
    }
    __syncthreads();
    int wv = tid >> 6, lane = tid & 63;
    int n0 = (blockIdx.x * 4 + wv) * TB;
    if (n0 >= N) return;
    float* slab = acs[wv];
    // stage: node j's 128 bf16 -> 128 f32 (lane covers 2 elems via one u32 load)
    #pragma unroll
    for (int j = 0; j < TB; ++j) {
        int n = n0 + j; if (n >= N) n = N - 1;
        u32 u = *(const u32*)&acbuf[(size_t)n * 128 + lane * 2];
        float2 f = make_float2(__uint_as_float(u << 16),
                               __uint_as_float(u & 0xffff0000u));
        *(float2*)&slab[j * 128 + lane * 2] = f;
    }
    float acc[TB] = {0.f, 0.f, 0.f, 0.f};
    #pragma unroll 4
    for (int kq = 0; kq < 16; ++kq) {
        float4 aq[TB], cq[TB];
        #pragma unroll
        for (int j = 0; j < TB; ++j) {
            aq[j] = *(const float4*)&slab[j * 128 + kq * 4];       // LDS broadcast
            cq[j] = *(const float4*)&slab[j * 128 + 64 + kq * 4];  // LDS broadcast
        }
        #pragma unroll
        for (int kk = 0; kk < 4; ++kk) {
            int k = kq * 4 + kk;
            float w1v = w1s[k * 64 + lane];
            float w2v = w2s[k * 64 + lane];
            #pragma unroll
            for (int j = 0; j < TB; ++j)
                acc[j] += (&aq[j].x)[kk] * w1v + (&cq[j].x)[kk] * w2v;
        }
    }
    float b1v = b1[lane], b2v = b2[lane];
    #pragma unroll
    for (int j = 0; j < TB; ++j) {
        int n = n0 + j;
        if (n >= N) break;
        float dgf = (float)(rp[n + 1] - rp[n]);
        float h = acc[j] + swbuf[n] * b1v + dgf * b2v;
        h = h >= 0.f ? h : 0.2f * h;
        float nsq = h * h;
        #pragma unroll
        for (int o = 32; o > 0; o >>= 1) nsq += __shfl_xor(nsq, o);
        float res = h / fmaxf(sqrtf(nsq), 1e-12f);
        out[(size_t)n * 64 + lane] = res;
        if (outb) outb[(size_t)n * 64 + lane] = f2bf(res);
    }
}

// ---- final gather of concatenated embeddings (float4) ----
__global__ void gather_kernel(const float* __restrict__ ue, const float* __restrict__ u1,
                              const float* __restrict__ u2, const float* __restrict__ ie,
                              const float* __restrict__ i1, const float* __restrict__ i2,
                              const int* __restrict__ users, const int* __restrict__ pos,
                              const int* __restrict__ neg, float4* __restrict__ out) {
    int idx = blockIdx.x * blockDim.x + threadIdx.x;     // float4 index
    if (idx >= 3 * NB * 48) return;
    int which = idx / (NB * 48);
    int rem = idx - which * (NB * 48);
    int b = rem / 48, c4 = rem - b * 48;                 // c4 in [0,48)
    int seg = c4 >> 4, cc = (c4 & 15) << 2;
    int row;
    const float* srcarr;
    if (which == 0) {
        row = users[b];
        srcarr = (seg == 0) ? ue : (seg == 1 ? u1 : u2);
    } else {
        row = (which == 1) ? pos[b] : neg[b];
        srcarr = (seg == 0) ? ie : (seg == 1 ? i1 : i2);
    }
    out[idx] = *(const float4*)&srcarr[(size_t)row * 64 + cc];
}

extern "C" void kernel_launch(void* const* d_in, const int* in_sizes, int n_in,
                              void* d_out, int out_size, void* d_ws, size_t ws_size,
                              hipStream_t stream) {
    const float* user_emb = (const float*)d_in[0];
    const float* item_emb = (const float*)d_in[1];
    const float* W1_0 = (const float*)d_in[2];
    const float* b1_0 = (const float*)d_in[3];
    const float* W2_0 = (const float*)d_in[4];
    const float* b2_0 = (const float*)d_in[5];
    const float* W1_1 = (const float*)d_in[6];
    const float* b1_1 = (const float*)d_in[7];
    const float* W2_1 = (const float*)d_in[8];
    const float* b2_1 = (const float*)d_in[9];
    const int* ei = (const int*)d_in[10];
    const int* users = (const int*)d_in[11];
    const int* pos = (const int*)d_in[12];
    const int* neg = (const int*)d_in[13];

    char* p = (char*)d_ws;
    int* du = (int*)p;          p += NU * 4;
    int* di = (int*)p;          p += NI * 4;
    float* rsd_u = (float*)p;   p += NU * 4;
    float* rsd_i = (float*)p;   p += NI * 4;
    int* psum = (int*)p;        p += (UB + IB) * 4;
    int* rp_u = (int*)p;        p += (NU + 1) * 4;
    int* rp_i = (int*)p;        p += (NI + 1) * 4;
    int* bcur_i = (int*)p;      p += NBKT_I * 4;
    int* bcur_u = (int*)p;      p += NBKT_U * 4;
    int2* csr8_u = (int2*)p;    p += (size_t)NE * 8;
    int2* csr8_i = (int2*)p;    p += (size_t)NE * 8;
    float* u1 = (float*)p;      p += (size_t)NU * 64 * 4;
    float* u2 = (float*)p;      p += (size_t)NU * 64 * 4;
    float* i1 = (float*)p;      p += (size_t)NI * 64 * 4;
    float* i2 = (float*)p;      p += (size_t)NI * 64 * 4;
    u16* acbuf_u = (u16*)p;     p += (size_t)NU * 128 * 2;   // bf16 now
    float* swbuf_u = (float*)p; p += NU * 4;
    float* swbuf_i = (float*)p; p += NI * 4;
    u16* u1b = (u16*)p;         p += (size_t)NU * 64 * 2;    // bf16 copy of u1
    u16* i1b = (u16*)p;         p += (size_t)NI * 64 * 2;    // bf16 copy of i1
    // aliases (dead-range proven):
    u16* acbuf_i = (u16*)u2;                             // u2[0 : 12.8MB]; dead before u2 written
    u16* ueb = (u16*)((char*)u2 + (size_t)NU * 64 * 2);  // u2[12.8 : 25.6MB]; dead after L0 gather
    u16* ieb = (u16*)i2;                                 // i2[0 : 6.4MB]; dead after L0 gather
    int2* pairI = (int2*)acbuf_u;                        // 16MB <= 25.6MB; dead before acbuf_u written
    int2* pairU = pairI + NE;

    // zero the degree counters (ws is re-poisoned before every call)
    hipMemsetAsync(du, 0, (size_t)(NU + NI) * sizeof(int), stream);

    convert_kernel<<<((NU + NI) * 16 + 255) / 256, 256, 0, stream>>>(
        (const float4*)user_emb, (const float4*)item_emb, (ushort4*)ueb, (ushort4*)ieb);
    deg_kernel<<<(NE + 255) / 256, 256, 0, stream>>>(ei, du, di);
    scan1_kernel<<<UB + IB, 1024, 0, stream>>>(du, di, psum, rsd_u, rsd_i);
    scan2_kernel<<<2, 128, 0, stream>>>(psum);
    scan3_kernel<<<UB + IB, 1024, 0, stream>>>(du, di, psum, rp_u, rp_i, bcur_u, bcur_i);
    binP1_kernel<<<(NE + EPB - 1) / EPB, 256, 0, stream>>>(ei, bcur_i, bcur_u, pairI, pairU);
    binP2_kernel<<<NBKT_I + NBKT_U, 256, 0, stream>>>(pairI, pairU, rp_i, rp_u,
                                                      rsd_u, rsd_i, csr8_i, csr8_u);

    const int GA = ((NI + NU) * 64 + 255) / 256;
    const int GB_I = (NI + 4 * TB - 1) / (4 * TB);
    const int GB_U = (NU + 4 * TB - 1) / (4 * TB);

    // ---- layer 0 ----
    gatherA_kernel<<<GA, 256, 0, stream>>>(user_emb, item_emb, ueb, ieb,
                                           rp_u, rp_i, csr8_u, csr8_i, rsd_u, rsd_i,
                                           acbuf_u, acbuf_i, swbuf_u, swbuf_i);
    transformB_kernel<<<GB_I, 256, 0, stream>>>(NI, acbuf_i, swbuf_i, rp_i,
                                                W1_0, b1_0, W2_0, b2_0, i1, i1b);
    transformB_kernel<<<GB_U, 256, 0, stream>>>(NU, acbuf_u, swbuf_u, rp_u,
                                                W1_0, b1_0, W2_0, b2_0, u1, u1b);
    // ---- layer 1 ----
    gatherA_kernel<<<GA, 256, 0, stream>>>(u1, i1, u1b, i1b,
                                           rp_u, rp_i, csr8_u, csr8_i, rsd_u, rsd_i,
                                           acbuf_u, acbuf_i, swbuf_u, swbuf_i);
    transformB_kernel<<<GB_I, 256, 0, stream>>>(NI, acbuf_i, swbuf_i, rp_i,
                                                W1_1, b1_1, W2_1, b2_1, i2, (u16*)nullptr);
    transformB_kernel<<<GB_U, 256, 0, stream>>>(NU, acbuf_u, swbuf_u, rp_u,
                                                W1_1, b1_1, W2_1, b2_1, u2, (u16*)nullptr);

    // ---- final gather ----
    gather_kernel<<<(3 * NB * 48 + 255) / 256, 256, 0, stream>>>(
        user_emb, u1, u2, item_emb, i1, i2, users, pos, neg, (float4*)d_out);
}